// Round 8
// baseline (280.640 us; speedup 1.0000x reference)
//
#include <hip/hip_runtime.h>
#include <stdint.h>

// EdgeNetwork, round 8: lane-parallel gather K2 (memory-level parallelism).
//   out[a] = K-contraction of S_a,  S_a = sum_{e:dst=a} bond_e (x) neigh_e.
// r6/r7 lesson: one-wave-per-atom SERIAL entry walk = 64 dependent ~900cyc
// round trips/wave = 77us regardless of read locality. Fix: lane l owns entry
// l -> 128 independent gathers issue concurrently (~2 round-trip walls), LDS
// stride-65 column transpose (conflict-free), S in regs, Kt read from L2
// (no staging, no barriers in K2). K1 back to id-bins, CSTR=16 (r7's CSTR=4
// packed 4 counters/line = 128-way line contention).

constexpr int DIM  = 16;
constexpr int CAP  = 64;     // slots/atom; P(deg>64) ~1e-8 at Poisson(32)
constexpr int CSTR = 16;     // counts stride (ints): one 64B line per counter
constexpr int OFLOW_CAP = 65536;

// ---- K1: bin {edge, src} per dst (8B entries, 5MB writes)
__global__ __launch_bounds__(256) void bin_id_kernel(
    const int* __restrict__ pair, int* __restrict__ counts,
    int* __restrict__ oflow_cnt, int* __restrict__ oflow,
    int2* __restrict__ bins, int n_edges)
{
    int e = blockIdx.x * blockDim.x + threadIdx.x;
    if (e >= n_edges) return;
    int2 pr = ((const int2*)pair)[e];                  // x=dst, y=src
    int r = atomicAdd(&counts[pr.x * CSTR], 1);
    if (r < CAP) bins[pr.x * CAP + r] = make_int2(e, pr.y);
    else { int oi = atomicAdd(oflow_cnt, 1); if (oi < OFLOW_CAP) oflow[oi] = e; }
}

// ---- K2: one wave per atom, lane-per-entry gather + LDS transpose.
// ebuf column-major: word addr = off*65 + lane (off 0..15 bond, 16..31 neigh).
// Writes: banks (off+l)%32, lanes l/l+32 alias -> 2-way (free).
// Reads (fixed t): bv 16 addrs x4-lane bcast; nv 4 addrs x16-lane bcast. Free.
__global__ __launch_bounds__(256) void atom_kernel(
    const float* __restrict__ atom, const float* __restrict__ bond,
    const float* __restrict__ kern, const float* __restrict__ bias,
    const int* __restrict__ counts, const int2* __restrict__ bins,
    float* __restrict__ out, int n_atoms)
{
    __shared__ float ebuf_all[4][32 * 65];   // 33,280 B: per-wave transpose buf
    __shared__ float Sl_all[4][272];         // per-wave S(256)+nsum(16)

    const int lane = threadIdx.x & 63;
    const int w    = threadIdx.x >> 6;
    const int a    = blockIdx.x * 4 + w;
    if (a >= n_atoms) return;                // no barriers below: safe early-out

    float* ebuf = ebuf_all[w];
    float* Sl   = Sl_all[w];

    const int deg = min(counts[a * CSTR], CAP);

    // ---- phase 0: lane-parallel independent gathers (all lines in flight)
    if (lane < deg) {
        int2 ent = bins[a * CAP + lane];               // coalesced 8B
        const float4* bp = (const float4*)(bond + (size_t)ent.x * DIM);
        const float4* ap = (const float4*)(atom + (size_t)ent.y * DIM);
        float4 b0 = bp[0], b1 = bp[1], b2 = bp[2], b3 = bp[3];
        float4 n0 = ap[0], n1 = ap[1], n2 = ap[2], n3 = ap[3];
        // column-major scatter into ebuf (2-way bank alias = free)
        ebuf[ 0 * 65 + lane] = b0.x; ebuf[ 1 * 65 + lane] = b0.y;
        ebuf[ 2 * 65 + lane] = b0.z; ebuf[ 3 * 65 + lane] = b0.w;
        ebuf[ 4 * 65 + lane] = b1.x; ebuf[ 5 * 65 + lane] = b1.y;
        ebuf[ 6 * 65 + lane] = b1.z; ebuf[ 7 * 65 + lane] = b1.w;
        ebuf[ 8 * 65 + lane] = b2.x; ebuf[ 9 * 65 + lane] = b2.y;
        ebuf[10 * 65 + lane] = b2.z; ebuf[11 * 65 + lane] = b2.w;
        ebuf[12 * 65 + lane] = b3.x; ebuf[13 * 65 + lane] = b3.y;
        ebuf[14 * 65 + lane] = b3.z; ebuf[15 * 65 + lane] = b3.w;
        ebuf[16 * 65 + lane] = n0.x; ebuf[17 * 65 + lane] = n0.y;
        ebuf[18 * 65 + lane] = n0.z; ebuf[19 * 65 + lane] = n0.w;
        ebuf[20 * 65 + lane] = n1.x; ebuf[21 * 65 + lane] = n1.y;
        ebuf[22 * 65 + lane] = n1.z; ebuf[23 * 65 + lane] = n1.w;
        ebuf[24 * 65 + lane] = n2.x; ebuf[25 * 65 + lane] = n2.y;
        ebuf[26 * 65 + lane] = n2.z; ebuf[27 * 65 + lane] = n2.w;
        ebuf[28 * 65 + lane] = n3.x; ebuf[29 * 65 + lane] = n3.y;
        ebuf[30 * 65 + lane] = n3.z; ebuf[31 * 65 + lane] = n3.w;
    }
    // wave-private LDS: compiler's lgkmcnt ordering suffices (no barrier)

    // ---- phase 1: rank-1 accumulate S from LDS (low-latency, pipelined)
    const int k4 = lane >> 2;          // S row (bond feature)
    const int j4 = (lane & 3) * 4;     // S col quarter
    float4 S4  = {0.f, 0.f, 0.f, 0.f};
    float4 ns4 = {0.f, 0.f, 0.f, 0.f};
#pragma unroll 4
    for (int t = 0; t < deg; ++t) {
        const float bv = ebuf[k4 * 65 + t];
        const float nx = ebuf[(16 + j4 + 0) * 65 + t];
        const float ny = ebuf[(16 + j4 + 1) * 65 + t];
        const float nz = ebuf[(16 + j4 + 2) * 65 + t];
        const float nw = ebuf[(16 + j4 + 3) * 65 + t];
        S4.x = fmaf(bv, nx, S4.x);
        S4.y = fmaf(bv, ny, S4.y);
        S4.z = fmaf(bv, nz, S4.z);
        S4.w = fmaf(bv, nw, S4.w);
        if (lane < 4) { ns4.x += nx; ns4.y += ny; ns4.z += nz; ns4.w += nw; }
    }
    *(float4*)&Sl[k4 * 16 + j4] = S4;
    if (lane < 4) *(float4*)&Sl[256 + j4] = ns4;

    // ---- phase 2: out[i] = sum_o Kt[o][i]*S[o]; Kt read straight from L2
    const int i = lane & 15, p = lane >> 4;
    float acc = 0.f;
#pragma unroll 8
    for (int q = 0; q < 64; ++q) {
        const int o = p + q * 4;                       // 0..255
        const int k = o >> 4, j = o & 15;
        acc = fmaf(kern[k * 256 + i * 16 + j], Sl[o], acc);
    }
#pragma unroll
    for (int q2 = 0; q2 < 4; ++q2) {
        const int jb = p + q2 * 4;                     // 0..15 (bias rows)
        acc = fmaf(bias[i * 16 + jb], Sl[256 + jb], acc);
    }
    acc += __shfl_xor(acc, 16, 64);
    acc += __shfl_xor(acc, 32, 64);
    if (lane < 16) out[(size_t)a * DIM + i] = acc;     // 64B coalesced
}

// ---- overflow fix-up (normally empty): exact f32 per edge, after atom pass
__global__ __launch_bounds__(256) void oflow_kernel(
    const float* __restrict__ atom, const float* __restrict__ bond,
    const int*   __restrict__ pair, const float* __restrict__ kern,
    const float* __restrict__ bias,
    const int* __restrict__ oflow_cnt, const int* __restrict__ oflow,
    float* __restrict__ out, int n_edges)
{
    int n = min(*oflow_cnt, OFLOW_CAP);
    for (int idx = blockIdx.x * blockDim.x + threadIdx.x; idx < n;
         idx += gridDim.x * blockDim.x) {
        int e = oflow[idx];
        int dst = pair[2 * e + 0], src = pair[2 * e + 1];
        float neigh[DIM], bnd[DIM], acc[DIM];
        for (int q = 0; q < DIM; ++q) neigh[q] = atom[(size_t)src * DIM + q];
        for (int q = 0; q < DIM; ++q) bnd[q]   = bond[(size_t)e * DIM + q];
#pragma unroll
        for (int ii = 0; ii < DIM; ++ii) {
            float d = 0.f;
#pragma unroll
            for (int j = 0; j < DIM; ++j) d = fmaf(bias[ii * DIM + j], neigh[j], d);
            acc[ii] = d;
        }
#pragma unroll 1
        for (int k = 0; k < DIM; ++k) {
            const float bk = bnd[k];
            const float* Kr = kern + k * 256;
#pragma unroll
            for (int ii = 0; ii < DIM; ++ii) {
                float d = 0.f;
#pragma unroll
                for (int j = 0; j < DIM; ++j) d = fmaf(Kr[ii * DIM + j], neigh[j], d);
                acc[ii] = fmaf(bk, d, acc[ii]);
            }
        }
#pragma unroll
        for (int ii = 0; ii < DIM; ++ii)
            atomicAdd(&out[(size_t)dst * DIM + ii], acc[ii]);
    }
}

// ---- fallback: plain atomic scatter (ws too small)
__global__ __launch_bounds__(256) void edge_atomic_kernel(
    const float* __restrict__ atom, const float* __restrict__ bond,
    const int*   __restrict__ pair, const float* __restrict__ kern,
    const float* __restrict__ bias, float* __restrict__ out, int n_edges)
{
    int e = blockIdx.x * blockDim.x + threadIdx.x;
    if (e >= n_edges) return;
    int dst = pair[2 * e + 0], src = pair[2 * e + 1];
    float neigh[DIM], bnd[DIM], acc[DIM];
    for (int q = 0; q < DIM; ++q) neigh[q] = atom[(size_t)src * DIM + q];
    for (int q = 0; q < DIM; ++q) bnd[q]   = bond[(size_t)e * DIM + q];
#pragma unroll
    for (int i = 0; i < DIM; ++i) {
        float d = 0.f;
#pragma unroll
        for (int j = 0; j < DIM; ++j) d = fmaf(bias[i * DIM + j], neigh[j], d);
        acc[i] = d;
    }
#pragma unroll 1
    for (int k = 0; k < DIM; ++k) {
        const float bk = bnd[k];
        const float* Kr = kern + k * 256;
#pragma unroll
        for (int i = 0; i < DIM; ++i) {
            float d = 0.f;
#pragma unroll
            for (int j = 0; j < DIM; ++j) d = fmaf(Kr[i * DIM + j], neigh[j], d);
            acc[i] = fmaf(bk, d, acc[i]);
        }
    }
#pragma unroll
    for (int i = 0; i < DIM; ++i) atomicAdd(&out[(size_t)dst * DIM + i], acc[i]);
}

extern "C" void kernel_launch(void* const* d_in, const int* in_sizes, int n_in,
                              void* d_out, int out_size, void* d_ws, size_t ws_size,
                              hipStream_t stream)
{
    const float* atom = (const float*)d_in[0];   // (20000,16) f32
    const float* bond = (const float*)d_in[1];   // (640000,16) f32
    const int*   pair = (const int*)d_in[2];     // (640000,2) i32 [dst, src]
    const float* kern = (const float*)d_in[3];   // (16,256) f32
    const float* bias = (const float*)d_in[4];   // (256,) f32
    float*       out  = (float*)d_out;           // (20000,16) f32

    const int n_edges = in_sizes[1] / DIM;       // 640000
    const int n_atoms = in_sizes[0] / DIM;       // 20000
    const int threads = 256;
    const int eblocks = (n_edges + threads - 1) / threads;
    const int ablocks = (n_atoms + 3) / 4;

    // ws: counts[n_atoms*CSTR] | oflow_cnt | oflow[OFLOW_CAP] | 64B | bins int2
    size_t counts_off = 0;
    size_t ocnt_off   = (size_t)n_atoms * CSTR * sizeof(int);
    size_t oflow_off  = ocnt_off + sizeof(int);
    size_t bins_off   = (oflow_off + (size_t)OFLOW_CAP * sizeof(int) + 63) & ~(size_t)63;
    size_t needed     = bins_off + (size_t)n_atoms * CAP * sizeof(int2);

    if (ws_size >= needed) {
        int*  counts    = (int*)((char*)d_ws + counts_off);
        int*  oflow_cnt = (int*)((char*)d_ws + ocnt_off);
        int*  oflow     = (int*)((char*)d_ws + oflow_off);
        int2* bins      = (int2*)((char*)d_ws + bins_off);

        hipMemsetAsync(counts, 0,
                       (size_t)n_atoms * CSTR * sizeof(int) + sizeof(int), stream);

        bin_id_kernel<<<eblocks, threads, 0, stream>>>(
            pair, counts, oflow_cnt, oflow, bins, n_edges);

        atom_kernel<<<ablocks, threads, 0, stream>>>(
            atom, bond, kern, bias, counts, bins, out, n_atoms);

        oflow_kernel<<<8, threads, 0, stream>>>(
            atom, bond, pair, kern, bias, oflow_cnt, oflow, out, n_edges);
    } else {
        hipMemsetAsync(out, 0, (size_t)out_size * sizeof(float), stream);
        edge_atomic_kernel<<<eblocks, threads, 0, stream>>>(
            atom, bond, pair, kern, bias, out, n_edges);
    }
}

// Round 10
// 163.073 us; speedup vs baseline: 1.7209x; 1.7209x over previous
//
#include <hip/hip_runtime.h>
#include <stdint.h>

// EdgeNetwork, round 9b (r9 + compile fix: stray "#pragma unroll 8 {}" removed).
//   out[a] = K-contraction of S_a,  S_a = sum_{e:dst=a} bond_e (x) neigh_e.
// Phase 0/1 (from r8, worked): lane-parallel gather -> column-major LDS ebuf
//   (stride 68: b128 quad-t reads, all aliasing <=2-way = free).
// Phase 2 (fixes r8's regression): r8 read kern with i-in-lane = 64 distinct
//   lines PER INSTRUCTION (340k line-reqs/CU = the whole 167us). Now K is
//   pre-transposed into ws (ktr[o*16+i], built by bin_kernel's first blocks);
//   dot loop reads 64 CONSECUTIVE dwords per instruction (1 coalesced 256B
//   L1-hit load). No Kt LDS -> ~39KB/block, zero barriers in atom_kernel.

constexpr int DIM  = 16;
constexpr int CAP  = 64;     // slots/atom; P(deg>64) ~1e-8 at Poisson(32)
constexpr int CSTR = 16;     // counts stride (ints): one 64B line per counter
constexpr int OFLOW_CAP = 65536;
constexpr int EST  = 68;     // ebuf column stride (words): %4==0 for b128, 2-way banks

// ---- K1: bin {edge, src} per dst; first 17 blocks also build ktr (4352 f32)
__global__ __launch_bounds__(256) void bin_id_kernel(
    const int* __restrict__ pair, const float* __restrict__ kern,
    const float* __restrict__ bias, float* __restrict__ ktr,
    int* __restrict__ counts, int* __restrict__ oflow_cnt, int* __restrict__ oflow,
    int2* __restrict__ bins, int n_edges)
{
    // fold the K-transpose in (saves a dispatch): ktr[o*16+i], o=(k*16+j) or 256+j
    int d = blockIdx.x * blockDim.x + threadIdx.x;
    if (d < 272 * 16) {
        const int o = d >> 4, i = d & 15;
        ktr[d] = (o < 256) ? kern[(o >> 4) * 256 + i * 16 + (o & 15)]
                           : bias[i * 16 + (o - 256)];
    }

    int e = blockIdx.x * blockDim.x + threadIdx.x;
    if (e >= n_edges) return;
    int2 pr = ((const int2*)pair)[e];                  // x=dst, y=src
    int r = atomicAdd(&counts[pr.x * CSTR], 1);
    if (r < CAP) bins[pr.x * CAP + r] = make_int2(e, pr.y);
    else { int oi = atomicAdd(oflow_cnt, 1); if (oi < OFLOW_CAP) oflow[oi] = e; }
}

// ---- K2: one wave per atom. Lane-parallel gather -> ebuf transpose ->
// rank-1 S accumulate (b128 quad-t) -> coalesced ktr dot. No barriers.
__global__ __launch_bounds__(256) void atom_kernel(
    const float* __restrict__ atom, const float* __restrict__ bond,
    const float* __restrict__ ktr, const int* __restrict__ counts,
    const int2* __restrict__ bins, float* __restrict__ out, int n_atoms)
{
    __shared__ float ebuf_all[4][32 * EST];  // 34,816 B: per-wave transpose buf
    __shared__ float Sl_all[4][272];         // per-wave S(256)+nsum(16): 4,352 B

    const int lane = threadIdx.x & 63;
    const int w    = threadIdx.x >> 6;
    const int a    = blockIdx.x * 4 + w;
    if (a >= n_atoms) return;                // no barriers below: safe early-out

    float* ebuf = ebuf_all[w];
    float* Sl   = Sl_all[w];

    const int deg = min(counts[a * CSTR], CAP);

    // ---- phase 0: lane-parallel independent gathers; zero-fill idle columns
    {
        float4 b0 = {0,0,0,0}, b1 = {0,0,0,0}, b2 = {0,0,0,0}, b3 = {0,0,0,0};
        float4 n0 = {0,0,0,0}, n1 = {0,0,0,0}, n2 = {0,0,0,0}, n3 = {0,0,0,0};
        if (lane < deg) {
            int2 ent = bins[a * CAP + lane];           // coalesced 8B
            const float4* bp = (const float4*)(bond + (size_t)ent.x * DIM);
            const float4* ap = (const float4*)(atom + (size_t)ent.y * DIM);
            b0 = bp[0]; b1 = bp[1]; b2 = bp[2]; b3 = bp[3];
            n0 = ap[0]; n1 = ap[1]; n2 = ap[2]; n3 = ap[3];
        }
        // column-major scatter (bank = (4*off+lane)%32: 2-way = free)
        ebuf[ 0*EST+lane]=b0.x; ebuf[ 1*EST+lane]=b0.y; ebuf[ 2*EST+lane]=b0.z; ebuf[ 3*EST+lane]=b0.w;
        ebuf[ 4*EST+lane]=b1.x; ebuf[ 5*EST+lane]=b1.y; ebuf[ 6*EST+lane]=b1.z; ebuf[ 7*EST+lane]=b1.w;
        ebuf[ 8*EST+lane]=b2.x; ebuf[ 9*EST+lane]=b2.y; ebuf[10*EST+lane]=b2.z; ebuf[11*EST+lane]=b2.w;
        ebuf[12*EST+lane]=b3.x; ebuf[13*EST+lane]=b3.y; ebuf[14*EST+lane]=b3.z; ebuf[15*EST+lane]=b3.w;
        ebuf[16*EST+lane]=n0.x; ebuf[17*EST+lane]=n0.y; ebuf[18*EST+lane]=n0.z; ebuf[19*EST+lane]=n0.w;
        ebuf[20*EST+lane]=n1.x; ebuf[21*EST+lane]=n1.y; ebuf[22*EST+lane]=n1.z; ebuf[23*EST+lane]=n1.w;
        ebuf[24*EST+lane]=n2.x; ebuf[25*EST+lane]=n2.y; ebuf[26*EST+lane]=n2.z; ebuf[27*EST+lane]=n2.w;
        ebuf[28*EST+lane]=n3.x; ebuf[29*EST+lane]=n3.y; ebuf[30*EST+lane]=n3.z; ebuf[31*EST+lane]=n3.w;
    }
    // wave-private LDS; compiler lgkmcnt ordering suffices (r8-proven)

    // ---- phase 1: rank-1 accumulate S, 4 edges per step via b128 reads
    const int k4 = lane >> 2;          // S row (bond feature)
    const int j4 = (lane & 3) * 4;     // S col quarter
    float4 S4  = {0.f, 0.f, 0.f, 0.f};
    float4 ns4 = {0.f, 0.f, 0.f, 0.f};
    const int quads = (deg + 3) >> 2;
#pragma unroll 4
    for (int tq = 0; tq < quads; ++tq) {
        const int t0 = tq * 4;
        const float4 bv  = *(const float4*)&ebuf[k4 * EST + t0];         // 2-way
        const float4 nv0 = *(const float4*)&ebuf[(16 + j4 + 0) * EST + t0];
        const float4 nv1 = *(const float4*)&ebuf[(16 + j4 + 1) * EST + t0];
        const float4 nv2 = *(const float4*)&ebuf[(16 + j4 + 2) * EST + t0];
        const float4 nv3 = *(const float4*)&ebuf[(16 + j4 + 3) * EST + t0];
        S4.x = fmaf(bv.x, nv0.x, fmaf(bv.y, nv0.y, fmaf(bv.z, nv0.z, fmaf(bv.w, nv0.w, S4.x))));
        S4.y = fmaf(bv.x, nv1.x, fmaf(bv.y, nv1.y, fmaf(bv.z, nv1.z, fmaf(bv.w, nv1.w, S4.y))));
        S4.z = fmaf(bv.x, nv2.x, fmaf(bv.y, nv2.y, fmaf(bv.z, nv2.z, fmaf(bv.w, nv2.w, S4.z))));
        S4.w = fmaf(bv.x, nv3.x, fmaf(bv.y, nv3.y, fmaf(bv.z, nv3.z, fmaf(bv.w, nv3.w, S4.w))));
        if (lane < 4) {                 // k4==0, j4=lane*4: nsum of 4 features
            ns4.x += nv0.x + nv0.y + nv0.z + nv0.w;
            ns4.y += nv1.x + nv1.y + nv1.z + nv1.w;
            ns4.z += nv2.x + nv2.y + nv2.z + nv2.w;
            ns4.w += nv3.x + nv3.y + nv3.z + nv3.w;
        }
    }
    *(float4*)&Sl[k4 * 16 + j4] = S4;           // 2-way banks, 16B aligned
    if (lane < 4) *(float4*)&Sl[256 + j4] = ns4;

    // ---- phase 2: out[i] = sum_o ktr[o][i] * Sl[o]; ktr read is ONE
    // coalesced 256B L1-hit load per instruction (lanes = 64 consecutive dwords)
    const int i = lane & 15, p = lane >> 4;
    float acc = 0.f;
#pragma unroll 4
    for (int q = 0; q < 68; ++q) {
        const int o = p + q * 4;                       // 0..271
        acc = fmaf(ktr[o * 16 + i], Sl[o], acc);       // Sl: broadcast (free)
    }
    acc += __shfl_xor(acc, 16, 64);
    acc += __shfl_xor(acc, 32, 64);
    if (lane < 16) out[(size_t)a * DIM + i] = acc;     // 64B coalesced
}

// ---- overflow fix-up (normally empty): exact f32 per edge, after atom pass
__global__ __launch_bounds__(256) void oflow_kernel(
    const float* __restrict__ atom, const float* __restrict__ bond,
    const int*   __restrict__ pair, const float* __restrict__ kern,
    const float* __restrict__ bias,
    const int* __restrict__ oflow_cnt, const int* __restrict__ oflow,
    float* __restrict__ out, int n_edges)
{
    int n = min(*oflow_cnt, OFLOW_CAP);
    for (int idx = blockIdx.x * blockDim.x + threadIdx.x; idx < n;
         idx += gridDim.x * blockDim.x) {
        int e = oflow[idx];
        int dst = pair[2 * e + 0], src = pair[2 * e + 1];
        float neigh[DIM], bnd[DIM], acc[DIM];
        for (int q = 0; q < DIM; ++q) neigh[q] = atom[(size_t)src * DIM + q];
        for (int q = 0; q < DIM; ++q) bnd[q]   = bond[(size_t)e * DIM + q];
#pragma unroll
        for (int ii = 0; ii < DIM; ++ii) {
            float d = 0.f;
#pragma unroll
            for (int j = 0; j < DIM; ++j) d = fmaf(bias[ii * DIM + j], neigh[j], d);
            acc[ii] = d;
        }
#pragma unroll 1
        for (int k = 0; k < DIM; ++k) {
            const float bk = bnd[k];
            const float* Kr = kern + k * 256;
#pragma unroll
            for (int ii = 0; ii < DIM; ++ii) {
                float d = 0.f;
#pragma unroll
                for (int j = 0; j < DIM; ++j) d = fmaf(Kr[ii * DIM + j], neigh[j], d);
                acc[ii] = fmaf(bk, d, acc[ii]);
            }
        }
#pragma unroll
        for (int ii = 0; ii < DIM; ++ii)
            atomicAdd(&out[(size_t)dst * DIM + ii], acc[ii]);
    }
}

// ---- fallback: plain atomic scatter (ws too small)
__global__ __launch_bounds__(256) void edge_atomic_kernel(
    const float* __restrict__ atom, const float* __restrict__ bond,
    const int*   __restrict__ pair, const float* __restrict__ kern,
    const float* __restrict__ bias, float* __restrict__ out, int n_edges)
{
    int e = blockIdx.x * blockDim.x + threadIdx.x;
    if (e >= n_edges) return;
    int dst = pair[2 * e + 0], src = pair[2 * e + 1];
    float neigh[DIM], bnd[DIM], acc[DIM];
    for (int q = 0; q < DIM; ++q) neigh[q] = atom[(size_t)src * DIM + q];
    for (int q = 0; q < DIM; ++q) bnd[q]   = bond[(size_t)e * DIM + q];
#pragma unroll
    for (int i = 0; i < DIM; ++i) {
        float d = 0.f;
#pragma unroll
        for (int j = 0; j < DIM; ++j) d = fmaf(bias[i * DIM + j], neigh[j], d);
        acc[i] = d;
    }
#pragma unroll 1
    for (int k = 0; k < DIM; ++k) {
        const float bk = bnd[k];
        const float* Kr = kern + k * 256;
#pragma unroll
        for (int i = 0; i < DIM; ++i) {
            float d = 0.f;
#pragma unroll
            for (int j = 0; j < DIM; ++j) d = fmaf(Kr[i * DIM + j], neigh[j], d);
            acc[i] = fmaf(bk, d, acc[i]);
        }
    }
#pragma unroll
    for (int i = 0; i < DIM; ++i) atomicAdd(&out[(size_t)dst * DIM + i], acc[i]);
}

extern "C" void kernel_launch(void* const* d_in, const int* in_sizes, int n_in,
                              void* d_out, int out_size, void* d_ws, size_t ws_size,
                              hipStream_t stream)
{
    const float* atom = (const float*)d_in[0];   // (20000,16) f32
    const float* bond = (const float*)d_in[1];   // (640000,16) f32
    const int*   pair = (const int*)d_in[2];     // (640000,2) i32 [dst, src]
    const float* kern = (const float*)d_in[3];   // (16,256) f32
    const float* bias = (const float*)d_in[4];   // (256,) f32
    float*       out  = (float*)d_out;           // (20000,16) f32

    const int n_edges = in_sizes[1] / DIM;       // 640000
    const int n_atoms = in_sizes[0] / DIM;       // 20000
    const int threads = 256;
    const int eblocks = (n_edges + threads - 1) / threads;
    const int ablocks = (n_atoms + 3) / 4;

    // ws: counts[n_atoms*CSTR] | oflow_cnt | oflow | 64B | ktr[4352] | bins int2
    size_t counts_off = 0;
    size_t ocnt_off   = (size_t)n_atoms * CSTR * sizeof(int);
    size_t oflow_off  = ocnt_off + sizeof(int);
    size_t ktr_off    = (oflow_off + (size_t)OFLOW_CAP * sizeof(int) + 63) & ~(size_t)63;
    size_t bins_off   = (ktr_off + 272 * 16 * sizeof(float) + 63) & ~(size_t)63;
    size_t needed     = bins_off + (size_t)n_atoms * CAP * sizeof(int2);

    if (ws_size >= needed) {
        int*   counts    = (int*)((char*)d_ws + counts_off);
        int*   oflow_cnt = (int*)((char*)d_ws + ocnt_off);
        int*   oflow     = (int*)((char*)d_ws + oflow_off);
        float* ktr       = (float*)((char*)d_ws + ktr_off);
        int2*  bins      = (int2*)((char*)d_ws + bins_off);

        (void)hipMemsetAsync(counts, 0,
                       (size_t)n_atoms * CSTR * sizeof(int) + sizeof(int), stream);

        bin_id_kernel<<<eblocks, threads, 0, stream>>>(
            pair, kern, bias, ktr, counts, oflow_cnt, oflow, bins, n_edges);

        atom_kernel<<<ablocks, threads, 0, stream>>>(
            atom, bond, ktr, counts, bins, out, n_atoms);

        oflow_kernel<<<8, threads, 0, stream>>>(
            atom, bond, pair, kern, bias, oflow_cnt, oflow, out, n_edges);
    } else {
        (void)hipMemsetAsync(out, 0, (size_t)out_size * sizeof(float), stream);
        edge_atomic_kernel<<<eblocks, threads, 0, stream>>>(
            atom, bond, pair, kern, bias, out, n_edges);
    }
}